// Round 5
// baseline (667.254 us; speedup 1.0000x reference)
//
#include <hip/hip_runtime.h>
#include <stdint.h>
#include <stddef.h>

#define DIM 256
#define NB 16
#define HH 56
#define WW 56
#define HWP (HH*WW)          // 3136
#define PH 62
#define PW 62
#define NPIX (NB*HWP)        // 50176
#define EPSV 1e-5f

using f32x4  = __attribute__((ext_vector_type(4))) float;
using bf16x8 = __attribute__((ext_vector_type(8))) __bf16;

static __device__ __forceinline__ unsigned short f2bf(float f) {
    union { float f; unsigned u; } v; v.f = f;
    unsigned r = v.u + 0x7FFFu + ((v.u >> 16) & 1u);
    return (unsigned short)(r >> 16);
}
static __device__ __forceinline__ float bf2f(unsigned short u) {
    union { unsigned u; float f; } v; v.u = ((unsigned)u) << 16; return v.f;
}
static __device__ __forceinline__ float silu_f(float z) {
    return z / (1.f + __expf(-z));
}

// ---------------- P1: fold BN into weights, merge 1x1 into 3x3 center, merge depthwise ----
__global__ void prep_weights(
    const float* __restrict__ w3, const float* __restrict__ g1, const float* __restrict__ b1,
    const float* __restrict__ m1, const float* __restrict__ v1, const float* __restrict__ w1,
    const float* __restrict__ g2, const float* __restrict__ b2, const float* __restrict__ m2,
    const float* __restrict__ v2, const float* __restrict__ dw7, const float* __restrict__ dwk,
    const float* __restrict__ g3, const float* __restrict__ b3, const float* __restrict__ m3,
    const float* __restrict__ v3,
    unsigned short* __restrict__ WkT, float* __restrict__ dwm, float* __restrict__ biasm,
    float* __restrict__ sc3, float* __restrict__ bi3)
{
    int co = blockIdx.x, t = threadIdx.x;          // t = ci
    float s1 = g1[co] * rsqrtf(v1[co] + EPSV);
    float s2 = g2[co] * rsqrtf(v2[co] + EPSV);
    float w1v = w1[co*DIM + t] * s2;
    const float* w3r = w3 + (size_t)(co*DIM + t)*9;
#pragma unroll
    for (int s = 0; s < 9; ++s) {
        float v = w3r[s]*s1 + (s == 4 ? w1v : 0.f);
        WkT[((size_t)s*DIM + co)*DIM + t] = f2bf(v);   // layout [tap][co][ci]
    }
    if (t < 49) dwm[co*49 + t] = dw7[co*49 + t] + dwk[co*49 + t];
    if (t == 0) {
        biasm[co] = (b1[co] - m1[co]*s1) + (b2[co] - m2[co]*s2);
        float s3 = g3[co] * rsqrtf(v3[co] + EPSV);
        sc3[co] = s3;
        bi3[co] = b3[co] - m3[co]*s3;
    }
}

// ---------------- P2: x NCHW f32 -> padded NHWC bf16 (writes its own halo zeros) --------
__global__ void prep_xpad(const float* __restrict__ x, unsigned short* __restrict__ xpad)
{
    __shared__ float lds[64][57];
    int cc = blockIdx.x;      // 0..3 channel chunk of 64
    int ph = blockIdx.y;      // 0..61 padded row
    int b  = blockIdx.z;      // 0..15
    int t  = threadIdx.x;
    int c0 = cc*64;
    char* rowc = (char*)xpad + ((size_t)(b*PH + ph)*PW)*(DIM*2) + c0*2;

    if (ph < 3 || ph >= HH + 3) {
        uint4 z = {0u,0u,0u,0u};
#pragma unroll
        for (int j = 0; j < 2; ++j) {
            int idx = j*256 + t;
            if (idx < 496) {
                int pix = idx >> 3, q = idx & 7;
                *(uint4*)(rowc + (size_t)pix*(DIM*2) + q*16) = z;
            }
        }
        return;
    }
    if (t < 48) {
        int p = t >> 3, q = t & 7;
        int pw = (p < 3) ? p : (PW - 6 + p);       // 0,1,2, 59,60,61
        uint4 z = {0u,0u,0u,0u};
        *(uint4*)(rowc + (size_t)pw*(DIM*2) + q*16) = z;
    }
    int h = ph - 3;
#pragma unroll
    for (int j = 0; j < 14; ++j) {                   // 64*56 = 3584 = 14*256
        int idx = j*256 + t;
        int c = idx / 56, w = idx % 56;
        lds[c][w] = x[((size_t)(b*DIM + c0 + c)*HH + h)*WW + w];
    }
    __syncthreads();
#pragma unroll
    for (int j = 0; j < 7; ++j) {                    // 56*32 pairs = 1792 = 7*256
        int idx = j*256 + t;
        int w = idx >> 5, cp = idx & 31;
        unsigned lo = f2bf(lds[2*cp][w]);
        unsigned hi = f2bf(lds[2*cp+1][w]);
        unsigned val = lo | (hi << 16);
        *(unsigned*)(rowc + (size_t)(w + 3)*(DIM*2) + 4*cp) = val;
    }
}

// ---------------- P3: merged depthwise 7x7, vectorized LDS reads, 8-wide strips --------
__global__ void depthwise7(const float* __restrict__ x, const float* __restrict__ dwm,
                           unsigned short* __restrict__ dwout)
{
    __shared__ float plane[PH][64];                  // rows padded to 64 (16B-aligned vec reads)
    int c = blockIdx.x, b = blockIdx.y, t = threadIdx.x;
#pragma unroll
    for (int j = 0; j < 4; ++j) {
        int idx = j*256 + t;
        if (idx < 992) ((f32x4*)plane)[idx] = (f32x4){0.f,0.f,0.f,0.f};
    }
    __syncthreads();
    const float* xp = x + ((size_t)b*DIM + c)*HWP;
#pragma unroll
    for (int j = 0; j < 13; ++j) {
        int idx = j*256 + t;
        if (idx < HWP) {
            int h = idx / 56, w = idx % 56;
            plane[h + 3][w + 3] = xp[idx];
        }
    }
    float wr[49];
#pragma unroll
    for (int i = 0; i < 49; ++i) wr[i] = dwm[c*49 + i];   // uniform -> SGPR
    __syncthreads();
    unsigned short* op = dwout + ((size_t)b*DIM + c)*HWP;
#pragma unroll
    for (int j = 0; j < 2; ++j) {                    // 392 octs = 56 rows x 7
        int q = j*256 + t;
        if (q < 392) {
            int h = q / 7, w0 = (q % 7)*8;
            float a[8] = {0.f,0.f,0.f,0.f,0.f,0.f,0.f,0.f};
#pragma unroll
            for (int dy = 0; dy < 7; ++dy) {
                const float* row = &plane[h + dy][w0];
                union { f32x4 v[4]; float s[16]; } rr;
                rr.v[0] = *(const f32x4*)(row);
                rr.v[1] = *(const f32x4*)(row + 4);
                rr.v[2] = *(const f32x4*)(row + 8);
                rr.v[3] = *(const f32x4*)(row + 12);
#pragma unroll
                for (int dx = 0; dx < 7; ++dx) {
                    float wv = wr[dy*7 + dx];
#pragma unroll
                    for (int o = 0; o < 8; ++o) a[o] += rr.s[dx + o] * wv;
                }
            }
            uint4 pk;
            pk.x = (unsigned)f2bf(a[0]) | ((unsigned)f2bf(a[1]) << 16);
            pk.y = (unsigned)f2bf(a[2]) | ((unsigned)f2bf(a[3]) << 16);
            pk.z = (unsigned)f2bf(a[4]) | ((unsigned)f2bf(a[5]) << 16);
            pk.w = (unsigned)f2bf(a[6]) | ((unsigned)f2bf(a[7]) << 16);
            *(uint4*)&op[h*WW + w0] = pk;
        }
    }
}

// ---------------- Main: implicit-GEMM conv3x3, 256x256 tile, 4-phase/K-tile pipeline ---
// 8 waves (2x4 per 128x128 quadrant). Phase = C-quadrant x K=64 (16 MFMA). Fragments are
// PHASE-LOCAL (a lives 2 phases = 32 VGPR, b reloaded = 16 VGPR) so acc's 128 AGPR +
// ~128 VGPR fit the 256-reg/wave cap (R4's spill bug). Each phase stages one half-tile
// of K-tile n+1 into the other slot; counted vmcnt(4) (never 0) at 3 of 4 phase ends.
__global__ __launch_bounds__(512, 2)
void main_conv(const unsigned short* __restrict__ xpad, const unsigned short* __restrict__ WkT,
               const unsigned short* __restrict__ dwo, const float* __restrict__ biasm,
               const float* __restrict__ sc3, const float* __restrict__ bi3,
               float* __restrict__ out)
{
    __shared__ __align__(16) char smem[131072];      // slot{0,1}: Ah0|Ah1|Bh0|Bh1 16K each
    int t = threadIdx.x;
    int lane = t & 63, wv = t >> 6;                  // 8 waves
    int wm = wv >> 2, wn = wv & 3;                   // 2 x 4 within a 128x128 quadrant
    int qm = lane & 15, qg = lane >> 4;
    int bx = blockIdx.x;

    int swz = (((t & 7) ^ ((t >> 3) & 7)) << 4);     // pre-swizzled source chunk

    uintptr_t gA4[2][2], gB2[2];
#pragma unroll
    for (int l = 0; l < 2; ++l) {
#pragma unroll
        for (int h = 0; h < 2; ++h) {
            int P = bx*256 + h*128 + l*64 + (t >> 3);
            int bb = P / HWP, rem = P % HWP;
            int hh = rem / WW, ww = rem % WW;
            gA4[l][h] = (uintptr_t)xpad + ((size_t)((bb*PH + hh + 2)*PW + (ww + 2))*DIM)*2 + swz;
        }
        gB2[l] = (uintptr_t)WkT + ((size_t)(l*64 + (t >> 3))*DIM)*2 + swz;
    }

    f32x4 acc[4][4][2] = {};                          // [quad(ih*2+jh)][fi][fc]
    bf16x8 afr[2][4], bfr[2][2];

    auto offsA = [&](int kt) { int s9 = kt >> 2, ch = kt & 3, ky = s9/3, kx = s9 - 3*ky;
                               return (ky*PW + kx)*(DIM*2) + ch*128; };
    auto offsB = [&](int kt) { int s9 = kt >> 2, ch = kt & 3;
                               return s9*(DIM*DIM*2) + ch*128; };

    auto STA = [&](int slot, int h, int offA) {
#pragma unroll
        for (int l = 0; l < 2; ++l)
            __builtin_amdgcn_global_load_lds(
                (const __attribute__((address_space(1))) void*)(gA4[l][h] + offA),
                (__attribute__((address_space(3))) void*)(smem + slot*65536 + h*16384
                    + (l*64 + (t >> 3))*128 + (t & 7)*16),
                16, 0, 0);
    };
    auto STB = [&](int slot, int h, int offB) {
#pragma unroll
        for (int l = 0; l < 2; ++l)
            __builtin_amdgcn_global_load_lds(
                (const __attribute__((address_space(1))) void*)(gB2[l] + offB + h*65536),
                (__attribute__((address_space(3))) void*)(smem + slot*65536 + 32768 + h*16384
                    + (l*64 + (t >> 3))*128 + (t & 7)*16),
                16, 0, 0);
    };
    auto LDA2 = [&](int slot, int ih) {
        const char* base = smem + slot*65536 + ih*16384 + (wm*64 + qm)*128;
#pragma unroll
        for (int kk = 0; kk < 2; ++kk)
#pragma unroll
            for (int fi = 0; fi < 4; ++fi)
                afr[kk][fi] = *(const bf16x8*)(base + fi*2048 + ((kk*64 + qg*16) ^ ((qm & 7) << 4)));
    };
    auto LDB2 = [&](int slot, int jh) {
        const char* base = smem + slot*65536 + 32768 + jh*16384 + (wn*32 + qm)*128;
#pragma unroll
        for (int kk = 0; kk < 2; ++kk)
#pragma unroll
            for (int fc = 0; fc < 2; ++fc)
                bfr[kk][fc] = *(const bf16x8*)(base + fc*2048 + ((kk*64 + qg*16) ^ ((qm & 7) << 4)));
    };
    auto MM = [&](int q) {
        __builtin_amdgcn_s_setprio(1);
#pragma unroll
        for (int kk = 0; kk < 2; ++kk)
#pragma unroll
            for (int fi = 0; fi < 4; ++fi)
#pragma unroll
                for (int fc = 0; fc < 2; ++fc)
                    acc[q][fi][fc] = __builtin_amdgcn_mfma_f32_16x16x32_bf16(
                        afr[kk][fi], bfr[kk][fc], acc[q][fi][fc], 0, 0, 0);
        __builtin_amdgcn_s_setprio(0);
        __builtin_amdgcn_sched_barrier(0);
    };

#define VMW4() asm volatile("s_waitcnt vmcnt(4)" ::: "memory")
#define VMW2() asm volatile("s_waitcnt vmcnt(2)" ::: "memory")
#define VMW0() asm volatile("s_waitcnt vmcnt(0)" ::: "memory")
#define BARM() { asm volatile("" ::: "memory"); __builtin_amdgcn_s_barrier(); asm volatile("" ::: "memory"); }

    // steady-state tile: compute K-tile in `slot`, stage K-tile n+1 into slot^1.
    // stage order: Ah0', Bh0', Bh1', Ah1'  (one half per phase)
    auto TILE = [&](int slot, int oAn, int oBn) {
        int o = slot ^ 1;
        // ph0: q0 = (i0,j0)
        STA(o, 0, oAn); LDA2(slot, 0); LDB2(slot, 0); MM(0);
        VMW4(); BARM();                      // publish Bh1(n) for ph1
        // ph1: q1 = (i0,j1)
        STB(o, 0, oBn); LDB2(slot, 1); MM(1);
        VMW4(); BARM();                      // publish Ah1(n) for ph2
        // ph2: q2 = (i1,j0)
        STB(o, 1, oBn); LDA2(slot, 1); LDB2(slot, 0); MM(2);
        BARM();                              // no wait needed
        // ph3: q3 = (i1,j1)
        STA(o, 1, oAn); LDB2(slot, 1); MM(3);
        VMW4(); BARM();                      // publish Ah0,Bh0(n+1) for next ph0
    };

    // prologue: stage K-tile 0 into slot0 (order Ah0,Bh0,Bh1,Ah1)
    STA(0, 0, offsA(0)); STB(0, 0, offsB(0)); STB(0, 1, offsB(0)); STA(0, 1, offsA(0));
    VMW4(); BARM();

#pragma unroll 1
    for (int i = 0; i < 17; ++i) {           // K-tiles 0..33, stage 1..34
        TILE(0, offsA(2*i + 1), offsB(2*i + 1));
        TILE(1, offsA(2*i + 2), offsB(2*i + 2));
    }
    TILE(0, offsA(35), offsB(35));           // K-tile 34, stages 35 into slot1

    // tail: K-tile 35 in slot1, no staging
    LDA2(1, 0); LDB2(1, 0); MM(0);
    VMW2(); BARM();                          // publish Bh1(35)
    LDB2(1, 1); MM(1);
    VMW0(); BARM();                          // publish Ah1(35)
    LDA2(1, 1); LDB2(1, 0); MM(2);
    LDB2(1, 1); MM(3);

#undef VMW4
#undef VMW2
#undef VMW0
#undef BARM

    // ---- epilogue: per-wave transpose through LDS (slot0 region; tail read slot1, and
    // all cross-wave slot0 reads ended >=1 barrier ago) ----
    float* ep = (float*)smem + wv*1088;               // 64 co-slots x 16 px, stride 17
#pragma unroll 1
    for (int ih = 0; ih < 2; ++ih) {
#pragma unroll 1
        for (int fi = 0; fi < 4; ++fi) {
#pragma unroll
            for (int jh = 0; jh < 2; ++jh)
#pragma unroll
                for (int fc = 0; fc < 2; ++fc) {
                    int cl = jh*2 + fc;
#pragma unroll
                    for (int r = 0; r < 4; ++r)
                        ep[(cl*16 + qm)*17 + 4*qg + r] = acc[ih*2 + jh][fi][fc][r];
                }
            int P = bx*256 + ih*128 + wm*64 + fi*16 + qm;   // this lane's pixel
            int bb = P / HWP, rem = P % HWP;
            size_t obase = (size_t)bb*DIM*HWP + rem;
#pragma unroll
            for (int j2 = 0; j2 < 16; ++j2) {
                int col = j2*4 + qg;                  // 0..63 co-slot
                int cl = col >> 4, cq = col & 15;
                int cog = (cl >> 1)*128 + wn*32 + (cl & 1)*16 + cq;
                float z = ep[col*17 + qm] + biasm[cog];
                float rep = silu_f(z);
                float y = rep + bf2f(dwo[obase + (size_t)cog*HWP]);
                float yy = y * sc3[cog] + bi3[cog];
                out[obase + (size_t)cog*HWP] = silu_f(yy);
            }
        }
    }
}

// ---------------- launch ----------------
extern "C" void kernel_launch(void* const* d_in, const int* in_sizes, int n_in,
                              void* d_out, int out_size, void* d_ws, size_t ws_size,
                              hipStream_t stream)
{
    (void)in_sizes; (void)n_in; (void)out_size; (void)ws_size;
    const float* x   = (const float*)d_in[0];
    const float* w3  = (const float*)d_in[1];
    const float* g1  = (const float*)d_in[2];
    const float* b1  = (const float*)d_in[3];
    const float* m1  = (const float*)d_in[4];
    const float* v1  = (const float*)d_in[5];
    const float* w1  = (const float*)d_in[6];
    const float* g2  = (const float*)d_in[7];
    const float* b2  = (const float*)d_in[8];
    const float* m2  = (const float*)d_in[9];
    const float* v2  = (const float*)d_in[10];
    const float* dw7 = (const float*)d_in[11];
    const float* dwk = (const float*)d_in[12];
    const float* g3  = (const float*)d_in[13];
    const float* b3  = (const float*)d_in[14];
    const float* m3  = (const float*)d_in[15];
    const float* v3  = (const float*)d_in[16];
    float* out = (float*)d_out;

    char* ws = (char*)d_ws;
    unsigned short* xpad = (unsigned short*)(ws);                 // 16*62*62*256*2 = 31,490,048
    unsigned short* WkT  = (unsigned short*)(ws + 31490048);      // 9*256*256*2    =  1,179,648
    unsigned short* dwo  = (unsigned short*)(ws + 32669696);      // 16*256*3136*2  = 25,690,112
    float* dwm   = (float*)(ws + 58359808);                       // 256*49*4
    float* biasm = (float*)(ws + 58409984);
    float* sc3   = (float*)(ws + 58411008);
    float* bi3   = (float*)(ws + 58412032);                       // end ~58.4 MB

    prep_weights<<<dim3(DIM), dim3(256), 0, stream>>>(
        w3, g1, b1, m1, v1, w1, g2, b2, m2, v2, dw7, dwk, g3, b3, m3, v3,
        WkT, dwm, biasm, sc3, bi3);
    prep_xpad<<<dim3(4, PH, NB), dim3(256), 0, stream>>>(x, xpad);
    depthwise7<<<dim3(DIM, NB), dim3(256), 0, stream>>>(x, dwm, dwo);
    main_conv<<<dim3(NPIX/256), dim3(512), 0, stream>>>(xpad, WkT, dwo, biasm, sc3, bi3, out);
}

// Round 6
// 212.752 us; speedup vs baseline: 3.1363x; 3.1363x over previous
//
#include <hip/hip_runtime.h>
#include <stdint.h>
#include <stddef.h>

#define DIM 256
#define NB 16
#define HH 56
#define WW 56
#define HWP (HH*WW)          // 3136
#define PH 62
#define PW 62
#define NPIX (NB*HWP)        // 50176
#define EPSV 1e-5f

using f32x4  = __attribute__((ext_vector_type(4))) float;
using bf16x8 = __attribute__((ext_vector_type(8))) __bf16;

static __device__ __forceinline__ unsigned short f2bf(float f) {
    union { float f; unsigned u; } v; v.f = f;
    unsigned r = v.u + 0x7FFFu + ((v.u >> 16) & 1u);
    return (unsigned short)(r >> 16);
}
static __device__ __forceinline__ float bf2f(unsigned short u) {
    union { unsigned u; float f; } v; v.u = ((unsigned)u) << 16; return v.f;
}
static __device__ __forceinline__ float silu_f(float z) {
    return z / (1.f + __expf(-z));
}

// ---------------- P1: fold BN into weights, merge 1x1 into 3x3 center, merge depthwise ----
__global__ void prep_weights(
    const float* __restrict__ w3, const float* __restrict__ g1, const float* __restrict__ b1,
    const float* __restrict__ m1, const float* __restrict__ v1, const float* __restrict__ w1,
    const float* __restrict__ g2, const float* __restrict__ b2, const float* __restrict__ m2,
    const float* __restrict__ v2, const float* __restrict__ dw7, const float* __restrict__ dwk,
    const float* __restrict__ g3, const float* __restrict__ b3, const float* __restrict__ m3,
    const float* __restrict__ v3,
    unsigned short* __restrict__ WkT, float* __restrict__ dwm, float* __restrict__ biasm,
    float* __restrict__ sc3, float* __restrict__ bi3)
{
    int co = blockIdx.x, t = threadIdx.x;          // t = ci
    float s1 = g1[co] * rsqrtf(v1[co] + EPSV);
    float s2 = g2[co] * rsqrtf(v2[co] + EPSV);
    float w1v = w1[co*DIM + t] * s2;
    const float* w3r = w3 + (size_t)(co*DIM + t)*9;
#pragma unroll
    for (int s = 0; s < 9; ++s) {
        float v = w3r[s]*s1 + (s == 4 ? w1v : 0.f);
        WkT[((size_t)s*DIM + co)*DIM + t] = f2bf(v);   // layout [tap][co][ci]
    }
    if (t < 49) dwm[co*49 + t] = dw7[co*49 + t] + dwk[co*49 + t];
    if (t == 0) {
        biasm[co] = (b1[co] - m1[co]*s1) + (b2[co] - m2[co]*s2);
        float s3 = g3[co] * rsqrtf(v3[co] + EPSV);
        sc3[co] = s3;
        bi3[co] = b3[co] - m3[co]*s3;
    }
}

// ---------------- P2: x NCHW f32 -> padded NHWC bf16 (writes its own halo zeros) --------
__global__ void prep_xpad(const float* __restrict__ x, unsigned short* __restrict__ xpad)
{
    __shared__ float lds[64][57];
    int cc = blockIdx.x;      // 0..3 channel chunk of 64
    int ph = blockIdx.y;      // 0..61 padded row
    int b  = blockIdx.z;      // 0..15
    int t  = threadIdx.x;
    int c0 = cc*64;
    char* rowc = (char*)xpad + ((size_t)(b*PH + ph)*PW)*(DIM*2) + c0*2;

    if (ph < 3 || ph >= HH + 3) {
        uint4 z = {0u,0u,0u,0u};
#pragma unroll
        for (int j = 0; j < 2; ++j) {
            int idx = j*256 + t;
            if (idx < 496) {
                int pix = idx >> 3, q = idx & 7;
                *(uint4*)(rowc + (size_t)pix*(DIM*2) + q*16) = z;
            }
        }
        return;
    }
    if (t < 48) {
        int p = t >> 3, q = t & 7;
        int pw = (p < 3) ? p : (PW - 6 + p);       // 0,1,2, 59,60,61
        uint4 z = {0u,0u,0u,0u};
        *(uint4*)(rowc + (size_t)pw*(DIM*2) + q*16) = z;
    }
    int h = ph - 3;
#pragma unroll
    for (int j = 0; j < 14; ++j) {                   // 64*56 = 3584 = 14*256
        int idx = j*256 + t;
        int c = idx / 56, w = idx % 56;
        lds[c][w] = x[((size_t)(b*DIM + c0 + c)*HH + h)*WW + w];
    }
    __syncthreads();
#pragma unroll
    for (int j = 0; j < 7; ++j) {                    // 56*32 pairs = 1792 = 7*256
        int idx = j*256 + t;
        int w = idx >> 5, cp = idx & 31;
        unsigned lo = f2bf(lds[2*cp][w]);
        unsigned hi = f2bf(lds[2*cp+1][w]);
        unsigned val = lo | (hi << 16);
        *(unsigned*)(rowc + (size_t)(w + 3)*(DIM*2) + 4*cp) = val;
    }
}

// ---------------- P3: merged depthwise 7x7, vectorized LDS reads, 8-wide strips --------
__global__ void depthwise7(const float* __restrict__ x, const float* __restrict__ dwm,
                           unsigned short* __restrict__ dwout)
{
    __shared__ float plane[PH][64];                  // rows padded to 64 (16B-aligned vec reads)
    int c = blockIdx.x, b = blockIdx.y, t = threadIdx.x;
#pragma unroll
    for (int j = 0; j < 4; ++j) {
        int idx = j*256 + t;
        if (idx < 992) ((f32x4*)plane)[idx] = (f32x4){0.f,0.f,0.f,0.f};
    }
    __syncthreads();
    const float* xp = x + ((size_t)b*DIM + c)*HWP;
#pragma unroll
    for (int j = 0; j < 13; ++j) {
        int idx = j*256 + t;
        if (idx < HWP) {
            int h = idx / 56, w = idx % 56;
            plane[h + 3][w + 3] = xp[idx];
        }
    }
    float wr[49];
#pragma unroll
    for (int i = 0; i < 49; ++i) wr[i] = dwm[c*49 + i];   // uniform -> SGPR
    __syncthreads();
    unsigned short* op = dwout + ((size_t)b*DIM + c)*HWP;
#pragma unroll
    for (int j = 0; j < 2; ++j) {                    // 392 octs = 56 rows x 7
        int q = j*256 + t;
        if (q < 392) {
            int h = q / 7, w0 = (q % 7)*8;
            float a[8] = {0.f,0.f,0.f,0.f,0.f,0.f,0.f,0.f};
#pragma unroll
            for (int dy = 0; dy < 7; ++dy) {
                const float* row = &plane[h + dy][w0];
                union { f32x4 v[4]; float s[16]; } rr;
                rr.v[0] = *(const f32x4*)(row);
                rr.v[1] = *(const f32x4*)(row + 4);
                rr.v[2] = *(const f32x4*)(row + 8);
                rr.v[3] = *(const f32x4*)(row + 12);
#pragma unroll
                for (int dx = 0; dx < 7; ++dx) {
                    float wv = wr[dy*7 + dx];
#pragma unroll
                    for (int o = 0; o < 8; ++o) a[o] += rr.s[dx + o] * wv;
                }
            }
            uint4 pk;
            pk.x = (unsigned)f2bf(a[0]) | ((unsigned)f2bf(a[1]) << 16);
            pk.y = (unsigned)f2bf(a[2]) | ((unsigned)f2bf(a[3]) << 16);
            pk.z = (unsigned)f2bf(a[4]) | ((unsigned)f2bf(a[5]) << 16);
            pk.w = (unsigned)f2bf(a[6]) | ((unsigned)f2bf(a[7]) << 16);
            *(uint4*)&op[h*WW + w0] = pk;
        }
    }
}

// ---------------- Main: implicit-GEMM conv3x3, 256x256 tile, 4-phase/K-tile pipeline ---
// Same schedule as R5 (validated correct). Accumulators are 32 NAMED f32x4 SSA values
// (macro-generated) and the epilogue is fully static -> no alloca, no scratch (R4/R5's
// 3 GB spill bug, rule #20). Counted vmcnt(4) (never 0) at 3 of 4 phase ends.
__global__ __launch_bounds__(512, 2)
void main_conv(const unsigned short* __restrict__ xpad, const unsigned short* __restrict__ WkT,
               const unsigned short* __restrict__ dwo, const float* __restrict__ biasm,
               const float* __restrict__ sc3, const float* __restrict__ bi3,
               float* __restrict__ out)
{
    __shared__ __align__(16) char smem[131072];      // slot{0,1}: Ah0|Ah1|Bh0|Bh1 16K each
    int t = threadIdx.x;
    int lane = t & 63, wv = t >> 6;                  // 8 waves
    int wm = wv >> 2, wn = wv & 3;                   // 2 x 4 within a 128x128 quadrant
    int qm = lane & 15, qg = lane >> 4;
    int bx = blockIdx.x;

    int swz = (((t & 7) ^ ((t >> 3) & 7)) << 4);     // pre-swizzled source chunk

    uintptr_t gA4[2][2], gB2[2];
#pragma unroll
    for (int l = 0; l < 2; ++l) {
#pragma unroll
        for (int h = 0; h < 2; ++h) {
            int P = bx*256 + h*128 + l*64 + (t >> 3);
            int bb = P / HWP, rem = P % HWP;
            int hh = rem / WW, ww = rem % WW;
            gA4[l][h] = (uintptr_t)xpad + ((size_t)((bb*PH + hh + 2)*PW + (ww + 2))*DIM)*2 + swz;
        }
        gB2[l] = (uintptr_t)WkT + ((size_t)(l*64 + (t >> 3))*DIM)*2 + swz;
    }

    // 32 named accumulators: ACC(q, fi, fc), q = quadrant (ih*2+jh), fi = A-frag, fc = B-frag
#define ACC(q,fi,fc) acc_##q##_##fi##_##fc
#define DECLQ(q) f32x4 ACC(q,0,0)={}, ACC(q,0,1)={}, ACC(q,1,0)={}, ACC(q,1,1)={}, \
                       ACC(q,2,0)={}, ACC(q,2,1)={}, ACC(q,3,0)={}, ACC(q,3,1)={};
    DECLQ(0) DECLQ(1) DECLQ(2) DECLQ(3)

    bf16x8 afr[2][4], bfr[2][2];

    auto offsA = [&](int kt) { int s9 = kt >> 2, ch = kt & 3, ky = s9/3, kx = s9 - 3*ky;
                               return (ky*PW + kx)*(DIM*2) + ch*128; };
    auto offsB = [&](int kt) { int s9 = kt >> 2, ch = kt & 3;
                               return s9*(DIM*DIM*2) + ch*128; };

    auto STA = [&](int slot, int h, int offA) {
#pragma unroll
        for (int l = 0; l < 2; ++l)
            __builtin_amdgcn_global_load_lds(
                (const __attribute__((address_space(1))) void*)(gA4[l][h] + offA),
                (__attribute__((address_space(3))) void*)(smem + slot*65536 + h*16384
                    + (l*64 + (t >> 3))*128 + (t & 7)*16),
                16, 0, 0);
    };
    auto STB = [&](int slot, int h, int offB) {
#pragma unroll
        for (int l = 0; l < 2; ++l)
            __builtin_amdgcn_global_load_lds(
                (const __attribute__((address_space(1))) void*)(gB2[l] + offB + h*65536),
                (__attribute__((address_space(3))) void*)(smem + slot*65536 + 32768 + h*16384
                    + (l*64 + (t >> 3))*128 + (t & 7)*16),
                16, 0, 0);
    };
    auto LDA2 = [&](int slot, int ih) {
        const char* base = smem + slot*65536 + ih*16384 + (wm*64 + qm)*128;
#pragma unroll
        for (int kk = 0; kk < 2; ++kk)
#pragma unroll
            for (int fi = 0; fi < 4; ++fi)
                afr[kk][fi] = *(const bf16x8*)(base + fi*2048 + ((kk*64 + qg*16) ^ ((qm & 7) << 4)));
    };
    auto LDB2 = [&](int slot, int jh) {
        const char* base = smem + slot*65536 + 32768 + jh*16384 + (wn*32 + qm)*128;
#pragma unroll
        for (int kk = 0; kk < 2; ++kk)
#pragma unroll
            for (int fc = 0; fc < 2; ++fc)
                bfr[kk][fc] = *(const bf16x8*)(base + fc*2048 + ((kk*64 + qg*16) ^ ((qm & 7) << 4)));
    };

#define MFMA_ __builtin_amdgcn_mfma_f32_16x16x32_bf16
#define MMKK(q,kk) \
    ACC(q,0,0) = MFMA_(afr[kk][0], bfr[kk][0], ACC(q,0,0), 0, 0, 0); \
    ACC(q,1,0) = MFMA_(afr[kk][1], bfr[kk][0], ACC(q,1,0), 0, 0, 0); \
    ACC(q,2,0) = MFMA_(afr[kk][2], bfr[kk][0], ACC(q,2,0), 0, 0, 0); \
    ACC(q,3,0) = MFMA_(afr[kk][3], bfr[kk][0], ACC(q,3,0), 0, 0, 0); \
    ACC(q,0,1) = MFMA_(afr[kk][0], bfr[kk][1], ACC(q,0,1), 0, 0, 0); \
    ACC(q,1,1) = MFMA_(afr[kk][1], bfr[kk][1], ACC(q,1,1), 0, 0, 0); \
    ACC(q,2,1) = MFMA_(afr[kk][2], bfr[kk][1], ACC(q,2,1), 0, 0, 0); \
    ACC(q,3,1) = MFMA_(afr[kk][3], bfr[kk][1], ACC(q,3,1), 0, 0, 0);
#define MM(q) { __builtin_amdgcn_s_setprio(1); MMKK(q,0) MMKK(q,1) \
                __builtin_amdgcn_s_setprio(0); __builtin_amdgcn_sched_barrier(0); }

#define VMW4() asm volatile("s_waitcnt vmcnt(4)" ::: "memory")
#define VMW2() asm volatile("s_waitcnt vmcnt(2)" ::: "memory")
#define VMW0() asm volatile("s_waitcnt vmcnt(0)" ::: "memory")
#define BARM() { asm volatile("" ::: "memory"); __builtin_amdgcn_s_barrier(); asm volatile("" ::: "memory"); }

    // steady-state K-tile: compute from `slot`, stage K-tile n+1 into slot^1.
    // stage order: Ah0', Bh0', Bh1', Ah1' (one half-tile per phase)
#define TILE(slot, oAn, oBn) { \
    STA(slot^1, 0, oAn); LDA2(slot, 0); LDB2(slot, 0); MM(0); VMW4(); BARM(); \
    STB(slot^1, 0, oBn); LDB2(slot, 1); MM(1); VMW4(); BARM(); \
    STB(slot^1, 1, oBn); LDA2(slot, 1); LDB2(slot, 0); MM(2); BARM(); \
    STA(slot^1, 1, oAn); LDB2(slot, 1); MM(3); VMW4(); BARM(); }

    // prologue: stage K-tile 0 into slot0 (order Ah0,Bh0,Bh1,Ah1)
    STA(0, 0, offsA(0)); STB(0, 0, offsB(0)); STB(0, 1, offsB(0)); STA(0, 1, offsA(0));
    VMW4(); BARM();

#pragma unroll 1
    for (int i = 0; i < 17; ++i) {           // K-tiles 0..33, staging 1..34
        TILE(0, offsA(2*i + 1), offsB(2*i + 1));
        TILE(1, offsA(2*i + 2), offsB(2*i + 2));
    }
    TILE(0, offsA(35), offsB(35));           // K-tile 34, stages 35 into slot1

    // tail: K-tile 35 in slot1, no staging
    LDA2(1, 0); LDB2(1, 0); MM(0);
    VMW2(); BARM();                          // publish Bh1(35)
    LDB2(1, 1); MM(1);
    VMW0(); BARM();                          // publish Ah1(35)
    LDA2(1, 1); LDB2(1, 0); MM(2);
    LDB2(1, 1); MM(3);

#undef TILE
#undef VMW4
#undef VMW2
#undef VMW0
#undef BARM

    // ---- epilogue: fully static (macro-instantiated); per-wave disjoint LDS region ----
    float* ep = (float*)smem + wv*1088;               // 64 co-slots x 16 px, stride 17
#define EPI(ih, fi, q0, q1) { \
    _Pragma("unroll") \
    for (int r = 0; r < 4; ++r) { \
        ep[( 0 + qm)*17 + 4*qg + r] = ACC(q0,fi,0)[r]; \
        ep[(16 + qm)*17 + 4*qg + r] = ACC(q0,fi,1)[r]; \
        ep[(32 + qm)*17 + 4*qg + r] = ACC(q1,fi,0)[r]; \
        ep[(48 + qm)*17 + 4*qg + r] = ACC(q1,fi,1)[r]; \
    } \
    int P = bx*256 + ih*128 + wm*64 + fi*16 + qm; \
    int bb = P / HWP, rem = P % HWP; \
    size_t obase = (size_t)bb*DIM*HWP + rem; \
    _Pragma("unroll") \
    for (int j2 = 0; j2 < 16; ++j2) { \
        int col = j2*4 + qg; \
        int cl = col >> 4, cq = col & 15; \
        int cog = (cl >> 1)*128 + wn*32 + (cl & 1)*16 + cq; \
        float z = ep[col*17 + qm] + biasm[cog]; \
        float rep = silu_f(z); \
        float y = rep + bf2f(dwo[obase + (size_t)cog*HWP]); \
        float yy = y * sc3[cog] + bi3[cog]; \
        out[obase + (size_t)cog*HWP] = silu_f(yy); \
    } }

    EPI(0, 0, 0, 1)
    EPI(0, 1, 0, 1)
    EPI(0, 2, 0, 1)
    EPI(0, 3, 0, 1)
    EPI(1, 0, 2, 3)
    EPI(1, 1, 2, 3)
    EPI(1, 2, 2, 3)
    EPI(1, 3, 2, 3)
#undef EPI
#undef MM
#undef MMKK
#undef MFMA_
#undef ACC
#undef DECLQ
}

// ---------------- launch ----------------
extern "C" void kernel_launch(void* const* d_in, const int* in_sizes, int n_in,
                              void* d_out, int out_size, void* d_ws, size_t ws_size,
                              hipStream_t stream)
{
    (void)in_sizes; (void)n_in; (void)out_size; (void)ws_size;
    const float* x   = (const float*)d_in[0];
    const float* w3  = (const float*)d_in[1];
    const float* g1  = (const float*)d_in[2];
    const float* b1  = (const float*)d_in[3];
    const float* m1  = (const float*)d_in[4];
    const float* v1  = (const float*)d_in[5];
    const float* w1  = (const float*)d_in[6];
    const float* g2  = (const float*)d_in[7];
    const float* b2  = (const float*)d_in[8];
    const float* m2  = (const float*)d_in[9];
    const float* v2  = (const float*)d_in[10];
    const float* dw7 = (const float*)d_in[11];
    const float* dwk = (const float*)d_in[12];
    const float* g3  = (const float*)d_in[13];
    const float* b3  = (const float*)d_in[14];
    const float* m3  = (const float*)d_in[15];
    const float* v3  = (const float*)d_in[16];
    float* out = (float*)d_out;

    char* ws = (char*)d_ws;
    unsigned short* xpad = (unsigned short*)(ws);                 // 16*62*62*256*2 = 31,490,048
    unsigned short* WkT  = (unsigned short*)(ws + 31490048);      // 9*256*256*2    =  1,179,648
    unsigned short* dwo  = (unsigned short*)(ws + 32669696);      // 16*256*3136*2  = 25,690,112
    float* dwm   = (float*)(ws + 58359808);                       // 256*49*4
    float* biasm = (float*)(ws + 58409984);
    float* sc3   = (float*)(ws + 58411008);
    float* bi3   = (float*)(ws + 58412032);                       // end ~58.4 MB

    prep_weights<<<dim3(DIM), dim3(256), 0, stream>>>(
        w3, g1, b1, m1, v1, w1, g2, b2, m2, v2, dw7, dwk, g3, b3, m3, v3,
        WkT, dwm, biasm, sc3, bi3);
    prep_xpad<<<dim3(4, PH, NB), dim3(256), 0, stream>>>(x, xpad);
    depthwise7<<<dim3(DIM, NB), dim3(256), 0, stream>>>(x, dwm, dwo);
    main_conv<<<dim3(NPIX/256), dim3(512), 0, stream>>>(xpad, WkT, dwo, biasm, sc3, bi3, out);
}

// Round 7
// 170.616 us; speedup vs baseline: 3.9108x; 1.2470x over previous
//
#include <hip/hip_runtime.h>
#include <stdint.h>
#include <stddef.h>

#define DIM 256
#define NB 16
#define HH 56
#define WW 56
#define HWP (HH*WW)          // 3136
#define PH 62
#define PW 62
#define NPIX (NB*HWP)        // 50176
#define EPSV 1e-5f

using f32x4  = __attribute__((ext_vector_type(4))) float;
using bf16x8 = __attribute__((ext_vector_type(8))) __bf16;

static __device__ __forceinline__ unsigned short f2bf(float f) {
    union { float f; unsigned u; } v; v.f = f;
    unsigned r = v.u + 0x7FFFu + ((v.u >> 16) & 1u);
    return (unsigned short)(r >> 16);
}
static __device__ __forceinline__ float bf2f(unsigned short u) {
    union { unsigned u; float f; } v; v.u = ((unsigned)u) << 16; return v.f;
}
static __device__ __forceinline__ float silu_f(float z) {
    return z / (1.f + __expf(-z));
}

// ---------------- P1: fold BN into weights, merge 1x1 into 3x3 center, merge depthwise ----
__global__ void prep_weights(
    const float* __restrict__ w3, const float* __restrict__ g1, const float* __restrict__ b1,
    const float* __restrict__ m1, const float* __restrict__ v1, const float* __restrict__ w1,
    const float* __restrict__ g2, const float* __restrict__ b2, const float* __restrict__ m2,
    const float* __restrict__ v2, const float* __restrict__ dw7, const float* __restrict__ dwk,
    const float* __restrict__ g3, const float* __restrict__ b3, const float* __restrict__ m3,
    const float* __restrict__ v3,
    unsigned short* __restrict__ WkT, float* __restrict__ dwm, float* __restrict__ biasm,
    float* __restrict__ sc3, float* __restrict__ bi3)
{
    int co = blockIdx.x, t = threadIdx.x;          // t = ci
    float s1 = g1[co] * rsqrtf(v1[co] + EPSV);
    float s2 = g2[co] * rsqrtf(v2[co] + EPSV);
    float w1v = w1[co*DIM + t] * s2;
    const float* w3r = w3 + (size_t)(co*DIM + t)*9;
#pragma unroll
    for (int s = 0; s < 9; ++s) {
        float v = w3r[s]*s1 + (s == 4 ? w1v : 0.f);
        WkT[((size_t)s*DIM + co)*DIM + t] = f2bf(v);   // layout [tap][co][ci]
    }
    if (t < 49) dwm[co*49 + t] = dw7[co*49 + t] + dwk[co*49 + t];
    if (t == 0) {
        biasm[co] = (b1[co] - m1[co]*s1) + (b2[co] - m2[co]*s2);
        float s3 = g3[co] * rsqrtf(v3[co] + EPSV);
        sc3[co] = s3;
        bi3[co] = b3[co] - m3[co]*s3;
    }
}

// ---------------- P2: x NCHW f32 -> padded NHWC bf16 (writes its own halo zeros) --------
__global__ void prep_xpad(const float* __restrict__ x, unsigned short* __restrict__ xpad)
{
    __shared__ float lds[64][57];
    int cc = blockIdx.x;      // 0..3 channel chunk of 64
    int ph = blockIdx.y;      // 0..61 padded row
    int b  = blockIdx.z;      // 0..15
    int t  = threadIdx.x;
    int c0 = cc*64;
    char* rowc = (char*)xpad + ((size_t)(b*PH + ph)*PW)*(DIM*2) + c0*2;

    if (ph < 3 || ph >= HH + 3) {
        uint4 z = {0u,0u,0u,0u};
#pragma unroll
        for (int j = 0; j < 2; ++j) {
            int idx = j*256 + t;
            if (idx < 496) {
                int pix = idx >> 3, q = idx & 7;
                *(uint4*)(rowc + (size_t)pix*(DIM*2) + q*16) = z;
            }
        }
        return;
    }
    if (t < 48) {
        int p = t >> 3, q = t & 7;
        int pw = (p < 3) ? p : (PW - 6 + p);       // 0,1,2, 59,60,61
        uint4 z = {0u,0u,0u,0u};
        *(uint4*)(rowc + (size_t)pw*(DIM*2) + q*16) = z;
    }
    int h = ph - 3;
#pragma unroll
    for (int j = 0; j < 14; ++j) {                   // 64*56 = 3584 = 14*256
        int idx = j*256 + t;
        int c = idx / 56, w = idx % 56;
        lds[c][w] = x[((size_t)(b*DIM + c0 + c)*HH + h)*WW + w];
    }
    __syncthreads();
#pragma unroll
    for (int j = 0; j < 7; ++j) {                    // 56*32 pairs = 1792 = 7*256
        int idx = j*256 + t;
        int w = idx >> 5, cp = idx & 31;
        unsigned lo = f2bf(lds[2*cp][w]);
        unsigned hi = f2bf(lds[2*cp+1][w]);
        unsigned val = lo | (hi << 16);
        *(unsigned*)(rowc + (size_t)(w + 3)*(DIM*2) + 4*cp) = val;
    }
}

// ---------------- P3: merged depthwise 7x7, vectorized LDS reads, 8-wide strips --------
__global__ void depthwise7(const float* __restrict__ x, const float* __restrict__ dwm,
                           unsigned short* __restrict__ dwout)
{
    __shared__ float plane[PH][64];                  // rows padded to 64 (16B-aligned vec reads)
    int c = blockIdx.x, b = blockIdx.y, t = threadIdx.x;
#pragma unroll
    for (int j = 0; j < 4; ++j) {
        int idx = j*256 + t;
        if (idx < 992) ((f32x4*)plane)[idx] = (f32x4){0.f,0.f,0.f,0.f};
    }
    __syncthreads();
    const float* xp = x + ((size_t)b*DIM + c)*HWP;
#pragma unroll
    for (int j = 0; j < 13; ++j) {
        int idx = j*256 + t;
        if (idx < HWP) {
            int h = idx / 56, w = idx % 56;
            plane[h + 3][w + 3] = xp[idx];
        }
    }
    float wr[49];
#pragma unroll
    for (int i = 0; i < 49; ++i) wr[i] = dwm[c*49 + i];   // uniform -> SGPR
    __syncthreads();
    unsigned short* op = dwout + ((size_t)b*DIM + c)*HWP;
#pragma unroll
    for (int j = 0; j < 2; ++j) {                    // 392 octs = 56 rows x 7
        int q = j*256 + t;
        if (q < 392) {
            int h = q / 7, w0 = (q % 7)*8;
            float a[8] = {0.f,0.f,0.f,0.f,0.f,0.f,0.f,0.f};
#pragma unroll
            for (int dy = 0; dy < 7; ++dy) {
                const float* row = &plane[h + dy][w0];
                union { f32x4 v[4]; float s[16]; } rr;
                rr.v[0] = *(const f32x4*)(row);
                rr.v[1] = *(const f32x4*)(row + 4);
                rr.v[2] = *(const f32x4*)(row + 8);
                rr.v[3] = *(const f32x4*)(row + 12);
#pragma unroll
                for (int dx = 0; dx < 7; ++dx) {
                    float wv = wr[dy*7 + dx];
#pragma unroll
                    for (int o = 0; o < 8; ++o) a[o] += rr.s[dx + o] * wv;
                }
            }
            uint4 pk;
            pk.x = (unsigned)f2bf(a[0]) | ((unsigned)f2bf(a[1]) << 16);
            pk.y = (unsigned)f2bf(a[2]) | ((unsigned)f2bf(a[3]) << 16);
            pk.z = (unsigned)f2bf(a[4]) | ((unsigned)f2bf(a[5]) << 16);
            pk.w = (unsigned)f2bf(a[6]) | ((unsigned)f2bf(a[7]) << 16);
            *(uint4*)&op[h*WW + w0] = pk;
        }
    }
}

// ---------------- Main: implicit-GEMM conv3x3, 128x128 tile, counted-vmcnt dbuf -------
// R2's proven structure (4 waves, VGPR~88, 2 blocks/CU => inter-block overlap) with the
// __syncthreads vmcnt(0) drain replaced by raw barrier + counted vmcnt(8): stage(s+1)'s
// 8 loads stay in flight across the whole compute(s) (T4, never drain to 0 in loop).
__global__ __launch_bounds__(256, 2)
void main_conv(const unsigned short* __restrict__ xpad, const unsigned short* __restrict__ WkT,
               const unsigned short* __restrict__ dwo, const float* __restrict__ biasm,
               const float* __restrict__ sc3, const float* __restrict__ bi3,
               float* __restrict__ out)
{
    __shared__ __align__(16) char smem[65536];       // buf{0,1}: A 16K + B 16K
    int t = threadIdx.x;
    int lane = t & 63, wv = t >> 6;
    int wm = wv >> 1, wn = wv & 1;
    int qm = lane & 15, qg = lane >> 4;

    int swz = (((lane & 7) ^ ((lane >> 3) & 7)) << 4);

    uintptr_t gA[4], gB[4];
#pragma unroll
    for (int r = 0; r < 4; ++r) {
        int pixt = r*32 + wv*8 + (lane >> 3);
        int P = blockIdx.x*128 + pixt;
        int bb = P / HWP, rem = P % HWP;
        int h = rem / WW, w = rem % WW;
        gA[r] = (uintptr_t)xpad + ((size_t)((bb*PH + h + 2)*PW + (w + 2))*DIM)*2 + swz;
        int cog = blockIdx.y*128 + pixt;
        gB[r] = (uintptr_t)WkT + ((size_t)cog*DIM)*2 + swz;
    }

    f32x4 acc[4][4] = {};

    auto stage = [&](int s, int buf) {
        int s9 = s >> 2, ch = s & 3;
        int ky = s9 / 3, kx = s9 - ky*3;
        int offA = (ky*PW + kx)*(DIM*2) + ch*128;
        int offB = s9*(DIM*DIM*2) + ch*128;
        char* base = smem + buf*32768;
#pragma unroll
        for (int r = 0; r < 4; ++r) {
            __builtin_amdgcn_global_load_lds(
                (const __attribute__((address_space(1))) void*)(gA[r] + offA),
                (__attribute__((address_space(3))) void*)(base + (r*32 + wv*8)*128),
                16, 0, 0);
            __builtin_amdgcn_global_load_lds(
                (const __attribute__((address_space(1))) void*)(gB[r] + offB),
                (__attribute__((address_space(3))) void*)(base + 16384 + (r*32 + wv*8)*128),
                16, 0, 0);
        }
    };

    int kxo = (qg << 4) ^ ((lane & 7) << 4);
    auto compute = [&](int buf) {
        const char* pA = smem + buf*32768 + (wm*64 + qm)*128;
        const char* pB = smem + buf*32768 + 16384 + (wn*64 + qm)*128;
#pragma unroll
        for (int kk = 0; kk < 2; ++kk) {
            int ko = kxo ^ (kk << 6);
            bf16x8 a[4], b[4];
#pragma unroll
            for (int i = 0; i < 4; ++i) {
                a[i] = *(const bf16x8*)(pA + i*2048 + ko);
                b[i] = *(const bf16x8*)(pB + i*2048 + ko);
            }
            __builtin_amdgcn_s_setprio(1);
#pragma unroll
            for (int i = 0; i < 4; ++i)
#pragma unroll
                for (int j = 0; j < 4; ++j)
                    acc[i][j] = __builtin_amdgcn_mfma_f32_16x16x32_bf16(a[i], b[j], acc[i][j], 0, 0, 0);
            __builtin_amdgcn_s_setprio(0);
        }
    };

#define VMW8() asm volatile("s_waitcnt vmcnt(8)" ::: "memory")
#define VMW0() asm volatile("s_waitcnt vmcnt(0)" ::: "memory")
#define BARX() { asm volatile("" ::: "memory"); __builtin_amdgcn_s_barrier(); asm volatile("" ::: "memory"); }

    stage(0, 0);
    stage(1, 1);
    VMW8(); BARX();                       // stage(0) landed & published
#pragma unroll 1
    for (int s = 0; s < 36; ++s) {
        compute(s & 1);                   // stage(s+1) flying underneath
        BARX();                           // all waves done reading buf (s&1)
        if (s <= 33) {
            stage(s + 2, s & 1);          // refill the buffer just freed
            VMW8();                       // stage(s+1) landed (8 newest = stage(s+2))
            BARX();                       // publish
        } else if (s == 34) {
            VMW0();                       // drain stage(35) for the last step
            BARX();
        }
    }
#undef VMW8
#undef VMW0
#undef BARX

    // ---- epilogue: per-wave transpose through LDS (disjoint regions, no barriers) ----
    float* ep = (float*)smem + wv*1088;               // 64 co x 16 pix, stride 17
#pragma unroll 1
    for (int mi = 0; mi < 4; ++mi) {
#pragma unroll
        for (int ni = 0; ni < 4; ++ni)
#pragma unroll
            for (int r = 0; r < 4; ++r)
                ep[(ni*16 + qm)*17 + 4*qg + r] = acc[mi][ni][r];
        int P = blockIdx.x*128 + wm*64 + mi*16 + qm;  // this lane's pixel
        int bb = P / HWP, rem = P % HWP;
        size_t obase = (size_t)bb*DIM*HWP + rem;
#pragma unroll
        for (int j = 0; j < 16; ++j) {
            int col = j*4 + qg;                       // 0..63 within wave's co range
            int cog = blockIdx.y*128 + wn*64 + col;
            float z = ep[col*17 + qm] + biasm[cog];
            float rep = silu_f(z);
            float y = rep + bf2f(dwo[obase + (size_t)cog*HWP]);
            float yy = y * sc3[cog] + bi3[cog];
            out[obase + (size_t)cog*HWP] = silu_f(yy);
        }
    }
}

// ---------------- launch ----------------
extern "C" void kernel_launch(void* const* d_in, const int* in_sizes, int n_in,
                              void* d_out, int out_size, void* d_ws, size_t ws_size,
                              hipStream_t stream)
{
    (void)in_sizes; (void)n_in; (void)out_size; (void)ws_size;
    const float* x   = (const float*)d_in[0];
    const float* w3  = (const float*)d_in[1];
    const float* g1  = (const float*)d_in[2];
    const float* b1  = (const float*)d_in[3];
    const float* m1  = (const float*)d_in[4];
    const float* v1  = (const float*)d_in[5];
    const float* w1  = (const float*)d_in[6];
    const float* g2  = (const float*)d_in[7];
    const float* b2  = (const float*)d_in[8];
    const float* m2  = (const float*)d_in[9];
    const float* v2  = (const float*)d_in[10];
    const float* dw7 = (const float*)d_in[11];
    const float* dwk = (const float*)d_in[12];
    const float* g3  = (const float*)d_in[13];
    const float* b3  = (const float*)d_in[14];
    const float* m3  = (const float*)d_in[15];
    const float* v3  = (const float*)d_in[16];
    float* out = (float*)d_out;

    char* ws = (char*)d_ws;
    unsigned short* xpad = (unsigned short*)(ws);                 // 16*62*62*256*2 = 31,490,048
    unsigned short* WkT  = (unsigned short*)(ws + 31490048);      // 9*256*256*2    =  1,179,648
    unsigned short* dwo  = (unsigned short*)(ws + 32669696);      // 16*256*3136*2  = 25,690,112
    float* dwm   = (float*)(ws + 58359808);                       // 256*49*4
    float* biasm = (float*)(ws + 58409984);
    float* sc3   = (float*)(ws + 58411008);
    float* bi3   = (float*)(ws + 58412032);                       // end ~58.4 MB

    prep_weights<<<dim3(DIM), dim3(256), 0, stream>>>(
        w3, g1, b1, m1, v1, w1, g2, b2, m2, v2, dw7, dwk, g3, b3, m3, v3,
        WkT, dwm, biasm, sc3, bi3);
    prep_xpad<<<dim3(4, PH, NB), dim3(256), 0, stream>>>(x, xpad);
    depthwise7<<<dim3(DIM, NB), dim3(256), 0, stream>>>(x, dwm, dwo);
    main_conv<<<dim3(NPIX/128, 2), dim3(256), 0, stream>>>(xpad, WkT, dwo, biasm, sc3, bi3, out);
}